// Round 4
// baseline (4190.939 us; speedup 1.0000x reference)
//
#include <hip/hip_runtime.h>
#include <stdint.h>

// LSTM: B=32, S=1024, I=H=512, 4H=2048
// Phase 1: x_gates = x @ W_ih^T + (b_ih + b_hh)   [bf16 MFMA GEMM]
// Phase 2: persistent cooperative kernel, 8 groups x 32 WGs, 4 batches/group.
//   W_hh slice now lives in LDS (128 KB fp32, stride-516 padded) — rounds 2/3
//   proved the register path unwinnable blind (VGPR stuck at 92, W spilled to
//   scratch, 531 MB FETCH). gfx950 LDS is 160 KB addressable per WG.
//   Barrier: per-WG monotonic flag dwords in one 128-B line per group, plain
//   relaxed agent-scope stores + one 32-lane poll load + ballot (replaces the
//   32 serialized atomic RMWs per step of rounds 1-3).

typedef __attribute__((ext_vector_type(8))) short bf16x8;
typedef __attribute__((ext_vector_type(4))) float f32x4;

__device__ __forceinline__ unsigned short f2bf(float f) {
  union { float f; unsigned u; } v; v.f = f;
  unsigned r = (v.u + 0x7fffu + ((v.u >> 16) & 1u)) >> 16;  // RNE
  return (unsigned short)r;
}
__device__ __forceinline__ float bf2f(unsigned short h) {
  union { unsigned u; float f; } v; v.u = ((unsigned)h) << 16;
  return v.f;
}

__global__ __launch_bounds__(256) void cvt_bf16(const float* __restrict__ in,
                                                unsigned short* __restrict__ out, int n) {
  int i = (blockIdx.x * 256 + threadIdx.x) * 4;
  if (i >= n) return;
  float4 v = *(const float4*)(in + i);
  ushort4 o;
  o.x = f2bf(v.x); o.y = f2bf(v.y); o.z = f2bf(v.z); o.w = f2bf(v.w);
  *(ushort4*)(out + i) = o;
}

// C[m][n] = sum_k A[m][k]*B[n][k] + b_ih[n] + b_hh[n], stored bf16.
__global__ __launch_bounds__(256) void gemm_xg(const unsigned short* __restrict__ A,
                                               const unsigned short* __restrict__ Bw,
                                               const float* __restrict__ b_ih,
                                               const float* __restrict__ b_hh,
                                               unsigned short* __restrict__ xg) {
  __shared__ unsigned short Asub[128][32];
  __shared__ unsigned short Bsub[128][32];
  const int tid = threadIdx.x;
  const int mb = blockIdx.x >> 4;
  const int nb = blockIdx.x & 15;
  const int wv = tid >> 6, ln = tid & 63;
  const int wr = wv >> 1, wc = wv & 1;
  const int lrow = tid >> 1;
  const int lseg = (tid & 1) * 16;

  const unsigned short* Ag = A + (size_t)(mb * 128 + lrow) * 512 + lseg;
  const unsigned short* Bg = Bw + (size_t)(nb * 128 + lrow) * 512 + lseg;

  f32x4 acc[4][4] = {};
  const int frow = ln & 15;
  const int kq = (ln >> 4) * 8;

  for (int k0 = 0; k0 < 512; k0 += 32) {
    uint4 a0 = *(const uint4*)(Ag + k0);
    uint4 a1 = *(const uint4*)(Ag + k0 + 8);
    uint4 b0 = *(const uint4*)(Bg + k0);
    uint4 b1 = *(const uint4*)(Bg + k0 + 8);
    __syncthreads();
    *(uint4*)&Asub[lrow][lseg]     = a0;
    *(uint4*)&Asub[lrow][lseg + 8] = a1;
    *(uint4*)&Bsub[lrow][lseg]     = b0;
    *(uint4*)&Bsub[lrow][lseg + 8] = b1;
    __syncthreads();
    bf16x8 af[4], bfr[4];
#pragma unroll
    for (int mi = 0; mi < 4; ++mi)
      af[mi] = *(const bf16x8*)&Asub[wr * 64 + mi * 16 + frow][kq];
#pragma unroll
    for (int ni = 0; ni < 4; ++ni)
      bfr[ni] = *(const bf16x8*)&Bsub[wc * 64 + ni * 16 + frow][kq];
#pragma unroll
    for (int mi = 0; mi < 4; ++mi)
#pragma unroll
      for (int ni = 0; ni < 4; ++ni)
        acc[mi][ni] = __builtin_amdgcn_mfma_f32_16x16x32_bf16(af[mi], bfr[ni], acc[mi][ni], 0, 0, 0);
  }

  const int col0 = nb * 128 + wc * 64 + frow;
  float bias[4];
#pragma unroll
  for (int ni = 0; ni < 4; ++ni)
    bias[ni] = b_ih[col0 + ni * 16] + b_hh[col0 + ni * 16];

#pragma unroll
  for (int mi = 0; mi < 4; ++mi) {
    const int m0 = mb * 128 + wr * 64 + mi * 16 + (ln >> 4) * 4;
#pragma unroll
    for (int ni = 0; ni < 4; ++ni) {
#pragma unroll
      for (int rr = 0; rr < 4; ++rr) {
        float v = acc[mi][ni][rr] + bias[ni];
        xg[(size_t)(m0 + rr) * 2048 + col0 + ni * 16] = f2bf(v);
      }
    }
  }
}

// Persistent recurrent kernel. Grid = 256 WGs (8 groups x 32), 256 threads.
// Group g owns batches [4g,4g+4); WG w owns h-indices [16w,16w+16).
// Thread (kc=tid>>6, r=tid&63) computes gate row grow(r) for 4 batches over
// k-chunk [kc*128, kc*128+128), reading W from LDS.
#define WSTRIDE 516  // 512 + 4-float pad: 16B-aligned, breaks bank alignment
__global__ __launch_bounds__(256) void lstm_rec(const unsigned short* __restrict__ xg,
                                                const float* __restrict__ W_hh,
                                                const float* __restrict__ h0,
                                                const float* __restrict__ c0,
                                                float* __restrict__ out,
                                                float* __restrict__ hn,
                                                float* __restrict__ cn,
                                                float* h_buf,          // [2][32][512]
                                                unsigned int* flags) { // [8][64], line/group
  __shared__ float W_lds[64 * WSTRIDE];  // 132,096 B
  __shared__ float h_lds[2048];          //   8,192 B
  __shared__ float scratch[64 * 17];     //   4,352 B
  __shared__ float gates_lds[64 * 5];    //   1,280 B
  __shared__ float c_lds[64];            //     256 B   (total ~146 KB < 160 KB)

  const int tid = threadIdx.x;
  const int g = blockIdx.x >> 5;
  const int w = blockIdx.x & 31;
  const int gb0 = g * 4;
  const int kc = tid >> 6;
  const int r = tid & 63;
  const int kcb = kc * 128;
  unsigned int* my_flags = flags + g * 64;  // 32 used dwords = one 128B line

  // One-time: stage this WG's 64 W_hh rows into LDS, coalesced.
  // Local row q*16+j  <->  global row q*512 + w*16 + j  (q=gate, j=0..15).
#pragma unroll
  for (int q = 0; q < 4; ++q) {
    const float* src = W_hh + ((size_t)q * 512 + w * 16) * 512;  // 16 rows x 512
    for (int u = tid * 4; u < 8192; u += 1024) {
      float4 v = *(const float4*)(src + u);
      int lr = q * 16 + (u >> 9);
      int col = u & 511;
      *(float4*)&W_lds[lr * WSTRIDE + col] = v;
    }
  }

  {
    const float* hp = h0 + gb0 * 512 + tid * 8;
    float4 va = *(const float4*)hp;
    float4 vb = *(const float4*)(hp + 4);
    *(float4*)&h_lds[tid * 8] = va;
    *(float4*)&h_lds[tid * 8 + 4] = vb;
    if (tid < 64) {
      int jj = tid & 15, bb = tid >> 4;
      c_lds[bb * 16 + jj] = c0[(gb0 + bb) * 512 + w * 16 + jj];
    }
  }
  __syncthreads();

  const float* Wp = &W_lds[r * WSTRIDE + kcb];
  const int grow = (r >> 4) * 512 + w * 16 + (r & 15);

  for (int t = 0; t < 1024; ++t) {
    // Issued at loop top, consumed after the FMA loop -> latency hidden.
    float xg_v = bf2f(xg[(size_t)((gb0 + kc) * 1024 + t) * 2048 + grow]);

    float acc0 = 0.f, acc1 = 0.f, acc2 = 0.f, acc3 = 0.f;
#pragma unroll
    for (int i = 0; i < 128; i += 4) {
      float4 wv = *(const float4*)(Wp + i);
      float4 ha = *(const float4*)&h_lds[kcb + i];
      float4 hb = *(const float4*)&h_lds[512 + kcb + i];
      float4 hc = *(const float4*)&h_lds[1024 + kcb + i];
      float4 hd = *(const float4*)&h_lds[1536 + kcb + i];
      acc0 = fmaf(wv.x, ha.x, acc0); acc0 = fmaf(wv.y, ha.y, acc0);
      acc0 = fmaf(wv.z, ha.z, acc0); acc0 = fmaf(wv.w, ha.w, acc0);
      acc1 = fmaf(wv.x, hb.x, acc1); acc1 = fmaf(wv.y, hb.y, acc1);
      acc1 = fmaf(wv.z, hb.z, acc1); acc1 = fmaf(wv.w, hb.w, acc1);
      acc2 = fmaf(wv.x, hc.x, acc2); acc2 = fmaf(wv.y, hc.y, acc2);
      acc2 = fmaf(wv.z, hc.z, acc2); acc2 = fmaf(wv.w, hc.w, acc2);
      acc3 = fmaf(wv.x, hd.x, acc3); acc3 = fmaf(wv.y, hd.y, acc3);
      acc3 = fmaf(wv.z, hd.z, acc3); acc3 = fmaf(wv.w, hd.w, acc3);
    }
    scratch[r * 17 + kc] = acc0;
    scratch[r * 17 + 4 + kc] = acc1;
    scratch[r * 17 + 8 + kc] = acc2;
    scratch[r * 17 + 12 + kc] = acc3;
    __syncthreads();

    {
      float s = xg_v + scratch[r * 17 + kc * 4] + scratch[r * 17 + kc * 4 + 1]
                     + scratch[r * 17 + kc * 4 + 2] + scratch[r * 17 + kc * 4 + 3];
      gates_lds[r * 5 + kc] = s;
    }
    __syncthreads();

    if (tid < 64) {
      const int jj = tid & 15, bb = tid >> 4;
      float gi = gates_lds[jj * 5 + bb];
      float gf = gates_lds[(16 + jj) * 5 + bb];
      float gc = gates_lds[(32 + jj) * 5 + bb];
      float go = gates_lds[(48 + jj) * 5 + bb];
      float ig = 1.f / (1.f + __expf(-gi));
      float fg = 1.f / (1.f + __expf(-gf));
      float gt = tanhf(gc);
      float og = 1.f / (1.f + __expf(-go));
      float c = fmaf(fg, c_lds[bb * 16 + jj], ig * gt);
      c_lds[bb * 16 + jj] = c;
      float hv = og * tanhf(c);
      out[(size_t)((gb0 + bb) * 1024 + t) * 512 + w * 16 + jj] = hv;
      __hip_atomic_store(&h_buf[((t + 1) & 1) * 16384 + (gb0 + bb) * 512 + w * 16 + jj], hv,
                         __ATOMIC_RELAXED, __HIP_MEMORY_SCOPE_AGENT);
      if (t == 1023) {
        hn[(gb0 + bb) * 512 + w * 16 + jj] = hv;
        cn[(gb0 + bb) * 512 + w * 16 + jj] = c;
      }
    }
    __syncthreads();  // wave 0's vmcnt(0) drain: h stores at LLC before flag fires

    if (t < 1023) {
      if (tid == 0)
        __hip_atomic_store(&my_flags[w], (unsigned)(t + 1),
                           __ATOMIC_RELAXED, __HIP_MEMORY_SCOPE_AGENT);
      if (tid < 32) {
        for (;;) {
          unsigned v = __hip_atomic_load(&my_flags[tid], __ATOMIC_RELAXED,
                                         __HIP_MEMORY_SCOPE_AGENT);
          if (__ballot(v > (unsigned)t) == 0xFFFFFFFFull) break;
          __builtin_amdgcn_s_sleep(1);
        }
      }
      __syncthreads();
      // Stage next h into LDS; 8-byte relaxed agent-scope loads (bypass L1).
      const unsigned long long* hb =
          (const unsigned long long*)(h_buf + ((t + 1) & 1) * 16384 + gb0 * 512 + tid * 8);
      unsigned long long v[4];
#pragma unroll
      for (int q = 0; q < 4; ++q)
        v[q] = __hip_atomic_load(hb + q, __ATOMIC_RELAXED, __HIP_MEMORY_SCOPE_AGENT);
#pragma unroll
      for (int q = 0; q < 4; ++q)
        *(unsigned long long*)&h_lds[tid * 8 + q * 2] = v[q];
      __syncthreads();
    }
  }
}

extern "C" void kernel_launch(void* const* d_in, const int* in_sizes, int n_in,
                              void* d_out, int out_size, void* d_ws, size_t ws_size,
                              hipStream_t stream) {
  const float* x    = (const float*)d_in[0];
  const float* W_ih = (const float*)d_in[1];
  const float* W_hh = (const float*)d_in[2];
  const float* b_ih = (const float*)d_in[3];
  const float* b_hh = (const float*)d_in[4];
  const float* h0   = (const float*)d_in[5];
  const float* c0   = (const float*)d_in[6];
  float* out = (float*)d_out;
  float* hn = out + (size_t)32 * 1024 * 512;
  float* cn = hn + 32 * 512;

  uint8_t* ws = (uint8_t*)d_ws;
  unsigned short* xg   = (unsigned short*)ws;                   // 134,217,728 B
  unsigned short* x_bf = (unsigned short*)(ws + 134217728u);    //  33,554,432 B
  unsigned short* w_bf = (unsigned short*)(ws + 167772160u);    //   2,097,152 B
  float* h_buf         = (float*)(ws + 169869312u);             //     131,072 B
  unsigned int* flags  = (unsigned int*)(ws + 170000384u);      //  8 * 256 B

  hipMemsetAsync(flags, 0, 8 * 256, stream);  // ws is poisoned 0xAA pre-launch
  cvt_bf16<<<dim3(16384), dim3(256), 0, stream>>>(x, x_bf, 16777216);
  cvt_bf16<<<dim3(1024), dim3(256), 0, stream>>>(W_ih, w_bf, 1048576);
  gemm_xg<<<dim3(4096), dim3(256), 0, stream>>>(x_bf, w_bf, b_ih, b_hh, xg);

  void* args[] = {(void*)&xg, (void*)&W_hh, (void*)&h0, (void*)&c0,
                  (void*)&out, (void*)&hn, (void*)&cn, (void*)&h_buf, (void*)&flags};
  hipLaunchCooperativeKernel((const void*)lstm_rec, dim3(256), dim3(256), args, 0, stream);
}

// Round 5
// 3949.269 us; speedup vs baseline: 1.0612x; 1.0612x over previous
//
#include <hip/hip_runtime.h>
#include <stdint.h>

// LSTM: B=32, S=1024, I=H=512, 4H=2048
// Phase 1: x_gates = x @ W_ih^T + (b_ih+b_hh)  [bf16 MFMA GEMM] written in a
//   PERMUTED layout [wg][t][batch][gate-row]: each recurrent WG reads one
//   contiguous 512B segment per step (round-4 FETCH=531MB = 4x over-fetch from
//   32B-segment reads on 128B lines).
// Phase 2: persistent cooperative kernel, 256 WGs x 512 threads (8 waves/CU).
//   8 groups x 32 WGs, 4 batches/group; W_hh slice (64 rows) in LDS fp32.
//   512 threads: 256 FMA/thread/step so VALU overlaps LDS across 8 waves
//   (round 4: 1 wave/SIMD serialized everything). Publish: wave0 stores h,
//   orders with inline s_waitcnt vmcnt(0), fires per-WG monotonic flag;
//   one wave polls 32 flags; relaxed agent-scope atomics throughout.

typedef __attribute__((ext_vector_type(8))) short bf16x8;
typedef __attribute__((ext_vector_type(4))) float f32x4;

__device__ __forceinline__ unsigned short f2bf(float f) {
  union { float f; unsigned u; } v; v.f = f;
  unsigned r = (v.u + 0x7fffu + ((v.u >> 16) & 1u)) >> 16;  // RNE
  return (unsigned short)r;
}
__device__ __forceinline__ float bf2f(unsigned short h) {
  union { unsigned u; float f; } v; v.u = ((unsigned)h) << 16;
  return v.f;
}

__global__ __launch_bounds__(256) void cvt_bf16(const float* __restrict__ in,
                                                unsigned short* __restrict__ out, int n) {
  int i = (blockIdx.x * 256 + threadIdx.x) * 4;
  if (i >= n) return;
  float4 v = *(const float4*)(in + i);
  ushort4 o;
  o.x = f2bf(v.x); o.y = f2bf(v.y); o.z = f2bf(v.z); o.w = f2bf(v.w);
  *(ushort4*)(out + i) = o;
}

// A: [32768][512] bf16 (x, m = b*1024+t), B: [2048][512] bf16 (W_ih).
// Output written permuted: idx = (((w*8+g)*1024 + t)*4 + bb)*64 + (q*16+j)
// where n = q*512 + w*16 + j, m = (g*4+bb)*1024 + t.
__global__ __launch_bounds__(256) void gemm_xg(const unsigned short* __restrict__ A,
                                               const unsigned short* __restrict__ Bw,
                                               const float* __restrict__ b_ih,
                                               const float* __restrict__ b_hh,
                                               unsigned short* __restrict__ xg) {
  __shared__ unsigned short Asub[128][32];
  __shared__ unsigned short Bsub[128][32];
  const int tid = threadIdx.x;
  const int mb = blockIdx.x >> 4;
  const int nb = blockIdx.x & 15;
  const int wv = tid >> 6, ln = tid & 63;
  const int wr = wv >> 1, wc = wv & 1;
  const int lrow = tid >> 1;
  const int lseg = (tid & 1) * 16;

  const unsigned short* Ag = A + (size_t)(mb * 128 + lrow) * 512 + lseg;
  const unsigned short* Bg = Bw + (size_t)(nb * 128 + lrow) * 512 + lseg;

  f32x4 acc[4][4] = {};
  const int frow = ln & 15;
  const int kq = (ln >> 4) * 8;

  for (int k0 = 0; k0 < 512; k0 += 32) {
    uint4 a0 = *(const uint4*)(Ag + k0);
    uint4 a1 = *(const uint4*)(Ag + k0 + 8);
    uint4 b0 = *(const uint4*)(Bg + k0);
    uint4 b1 = *(const uint4*)(Bg + k0 + 8);
    __syncthreads();
    *(uint4*)&Asub[lrow][lseg]     = a0;
    *(uint4*)&Asub[lrow][lseg + 8] = a1;
    *(uint4*)&Bsub[lrow][lseg]     = b0;
    *(uint4*)&Bsub[lrow][lseg + 8] = b1;
    __syncthreads();
    bf16x8 af[4], bfr[4];
#pragma unroll
    for (int mi = 0; mi < 4; ++mi)
      af[mi] = *(const bf16x8*)&Asub[wr * 64 + mi * 16 + frow][kq];
#pragma unroll
    for (int ni = 0; ni < 4; ++ni)
      bfr[ni] = *(const bf16x8*)&Bsub[wc * 64 + ni * 16 + frow][kq];
#pragma unroll
    for (int mi = 0; mi < 4; ++mi)
#pragma unroll
      for (int ni = 0; ni < 4; ++ni)
        acc[mi][ni] = __builtin_amdgcn_mfma_f32_16x16x32_bf16(af[mi], bfr[ni], acc[mi][ni], 0, 0, 0);
  }

  const int col0 = nb * 128 + wc * 64 + frow;
  float bias[4];
#pragma unroll
  for (int ni = 0; ni < 4; ++ni)
    bias[ni] = b_ih[col0 + ni * 16] + b_hh[col0 + ni * 16];

#pragma unroll
  for (int mi = 0; mi < 4; ++mi) {
    const int m0 = mb * 128 + wr * 64 + mi * 16 + (ln >> 4) * 4;  // D row = quad*4+reg
#pragma unroll
    for (int ni = 0; ni < 4; ++ni) {
      const int n = col0 + ni * 16;                 // D col = lane&15 within 16
      const int w_ = (n & 511) >> 4;
      const int r_ = ((n >> 9) << 4) + (n & 15);    // q*16 + j
#pragma unroll
      for (int rr = 0; rr < 4; ++rr) {
        const int m = m0 + rr;
        const int t = m & 1023;
        const int bg = m >> 10;                     // global batch
        const size_t idx =
            ((((size_t)(w_ * 8 + (bg >> 2)) << 10) + t) * 4 + (bg & 3)) * 64 + r_;
        xg[idx] = f2bf(acc[mi][ni][rr] + bias[ni]);
      }
    }
  }
}

// Persistent recurrent kernel. Grid = 256 WGs x 512 threads.
// g = blockIdx&7, w = blockIdx>>3 (XCD-local groups under round-robin dispatch
// — perf heuristic only). Group g owns batches [4g,4g+4); WG w owns h-indices
// [16w,16w+16). Matvec thread (kc=tid>>6 in 0..7, r=tid&63): gate row r over
// k-chunk [kc*64, kc*64+64), W from LDS, h broadcast from LDS.
#define WSTRIDE 516  // 512 + 4-float pad, 16B-aligned
__global__ __launch_bounds__(512, 1) void lstm_rec(const unsigned short* __restrict__ xg,
                                                   const float* __restrict__ W_hh,
                                                   const float* __restrict__ h0,
                                                   const float* __restrict__ c0,
                                                   float* __restrict__ out,
                                                   float* __restrict__ hn,
                                                   float* __restrict__ cn,
                                                   float* h_buf,          // [2][32][512]
                                                   unsigned int* flags) { // [8][64]
  __shared__ float W_lds[64 * WSTRIDE];  // 132,096 B
  __shared__ float h_lds[2048];          //   8,192 B  [b][k]
  __shared__ float scratch[64 * 33];     //   8,448 B  [r][b*8+kc]
  __shared__ float gates_lds[256];       //   1,024 B  [r][b] stride 4
  __shared__ float c_lds[64];            //     256 B  (total ~150 KB)

  const int tid = threadIdx.x;
  const int g = blockIdx.x & 7;
  const int w = blockIdx.x >> 3;
  const int gb0 = g * 4;
  const int kc = tid >> 6;
  const int r = tid & 63;
  const int kcb = kc * 64;
  unsigned int* my_flags = flags + g * 64;

  // One-time: stage 64 W_hh rows (4 gates x 16 cols of this w) into LDS.
#pragma unroll
  for (int q = 0; q < 4; ++q) {
    const float* src = W_hh + ((size_t)q * 512 + w * 16) * 512;  // 16 rows x 512
    for (int u = tid * 4; u < 8192; u += 2048) {
      float4 v = *(const float4*)(src + u);
      *(float4*)&W_lds[(q * 16 + (u >> 9)) * WSTRIDE + (u & 511)] = v;
    }
  }
  {
    float4 v = *(const float4*)(h0 + gb0 * 512 + tid * 4);
    *(float4*)&h_lds[tid * 4] = v;
    if (tid < 64)
      c_lds[tid] = c0[(gb0 + (tid >> 4)) * 512 + w * 16 + (tid & 15)];
  }
  __syncthreads();

  const float* Wp = &W_lds[r * WSTRIDE + kcb];
  const unsigned short* xgp = xg + (size_t)blockIdx.x * 262144;  // [t][b][r]

  for (int t = 0; t < 1024; ++t) {
    // xg for reduce role (b=tid>>6, row=tid&63); contiguous 512B per WG.
    float xg_v = 0.f;
    if (tid < 256) xg_v = bf2f(xgp[t * 256 + tid]);

    float acc0 = 0.f, acc1 = 0.f, acc2 = 0.f, acc3 = 0.f;
#pragma unroll
    for (int i = 0; i < 64; i += 4) {
      float4 wv = *(const float4*)(Wp + i);
      float4 ha = *(const float4*)&h_lds[kcb + i];
      float4 hb = *(const float4*)&h_lds[512 + kcb + i];
      float4 hc = *(const float4*)&h_lds[1024 + kcb + i];
      float4 hd = *(const float4*)&h_lds[1536 + kcb + i];
      acc0 = fmaf(wv.x, ha.x, acc0); acc0 = fmaf(wv.y, ha.y, acc0);
      acc0 = fmaf(wv.z, ha.z, acc0); acc0 = fmaf(wv.w, ha.w, acc0);
      acc1 = fmaf(wv.x, hb.x, acc1); acc1 = fmaf(wv.y, hb.y, acc1);
      acc1 = fmaf(wv.z, hb.z, acc1); acc1 = fmaf(wv.w, hb.w, acc1);
      acc2 = fmaf(wv.x, hc.x, acc2); acc2 = fmaf(wv.y, hc.y, acc2);
      acc2 = fmaf(wv.z, hc.z, acc2); acc2 = fmaf(wv.w, hc.w, acc2);
      acc3 = fmaf(wv.x, hd.x, acc3); acc3 = fmaf(wv.y, hd.y, acc3);
      acc3 = fmaf(wv.z, hd.z, acc3); acc3 = fmaf(wv.w, hd.w, acc3);
    }
    scratch[r * 33 + kc] = acc0;
    scratch[r * 33 + 8 + kc] = acc1;
    scratch[r * 33 + 16 + kc] = acc2;
    scratch[r * 33 + 24 + kc] = acc3;
    __syncthreads();

    if (tid < 256) {  // (b = tid>>6, row = tid&63): sum 8 k-chunk partials
      const int b = tid >> 6, row = tid & 63;
      const float* sp = &scratch[row * 33 + b * 8];
      float s = xg_v + sp[0] + sp[1] + sp[2] + sp[3] + sp[4] + sp[5] + sp[6] + sp[7];
      gates_lds[row * 4 + b] = s;
    }
    __syncthreads();

    if (tid < 64) {  // (jj = tid&15, bb = tid>>4): activations + state
      const int jj = tid & 15, bb = tid >> 4;
      float gi = gates_lds[(jj)      * 4 + bb];
      float gf = gates_lds[(16 + jj) * 4 + bb];
      float gc = gates_lds[(32 + jj) * 4 + bb];
      float go = gates_lds[(48 + jj) * 4 + bb];
      float ig = 1.f / (1.f + __expf(-gi));
      float fg = 1.f / (1.f + __expf(-gf));
      float gt = tanhf(gc);
      float og = 1.f / (1.f + __expf(-go));
      float c = fmaf(fg, c_lds[bb * 16 + jj], ig * gt);
      c_lds[bb * 16 + jj] = c;
      float hv = og * tanhf(c);
      out[(size_t)((gb0 + bb) * 1024 + t) * 512 + w * 16 + jj] = hv;
      __hip_atomic_store(&h_buf[((t + 1) & 1) * 16384 + (gb0 + bb) * 512 + w * 16 + jj], hv,
                         __ATOMIC_RELAXED, __HIP_MEMORY_SCOPE_AGENT);
      if (t == 1023) {
        hn[(gb0 + bb) * 512 + w * 16 + jj] = hv;
        cn[(gb0 + bb) * 512 + w * 16 + jj] = c;
      }
    }

    if (t < 1023) {
      // All step-t global stores were issued by wave 0 -> wave 0 alone can
      // order them and fire the flag (no whole-WG barrier on this path).
      if (tid == 0) {
        asm volatile("s_waitcnt vmcnt(0)" ::: "memory");
        __hip_atomic_store(&my_flags[w], (unsigned)(t + 1),
                           __ATOMIC_RELAXED, __HIP_MEMORY_SCOPE_AGENT);
      }
      if (tid < 32) {
        for (;;) {
          unsigned v = __hip_atomic_load(&my_flags[tid], __ATOMIC_RELAXED,
                                         __HIP_MEMORY_SCOPE_AGENT);
          if (__ballot(v > (unsigned)t) == 0xFFFFFFFFull) break;
          __builtin_amdgcn_s_sleep(1);
        }
      }
      __syncthreads();
      // Reload group's h(t+1): 2048 floats, 4/thread, 8B agent-scope loads.
      const unsigned long long* hb =
          (const unsigned long long*)(h_buf + ((t + 1) & 1) * 16384 + gb0 * 512 + tid * 4);
      unsigned long long v0 = __hip_atomic_load(hb, __ATOMIC_RELAXED, __HIP_MEMORY_SCOPE_AGENT);
      unsigned long long v1 = __hip_atomic_load(hb + 1, __ATOMIC_RELAXED, __HIP_MEMORY_SCOPE_AGENT);
      *(unsigned long long*)&h_lds[tid * 4] = v0;
      *(unsigned long long*)&h_lds[tid * 4 + 2] = v1;
      __syncthreads();
    }
  }
}

extern "C" void kernel_launch(void* const* d_in, const int* in_sizes, int n_in,
                              void* d_out, int out_size, void* d_ws, size_t ws_size,
                              hipStream_t stream) {
  const float* x    = (const float*)d_in[0];
  const float* W_ih = (const float*)d_in[1];
  const float* W_hh = (const float*)d_in[2];
  const float* b_ih = (const float*)d_in[3];
  const float* b_hh = (const float*)d_in[4];
  const float* h0   = (const float*)d_in[5];
  const float* c0   = (const float*)d_in[6];
  float* out = (float*)d_out;
  float* hn = out + (size_t)32 * 1024 * 512;
  float* cn = hn + 32 * 512;

  uint8_t* ws = (uint8_t*)d_ws;
  unsigned short* xg   = (unsigned short*)ws;                   // 134,217,728 B
  unsigned short* x_bf = (unsigned short*)(ws + 134217728u);    //  33,554,432 B
  unsigned short* w_bf = (unsigned short*)(ws + 167772160u);    //   2,097,152 B
  float* h_buf         = (float*)(ws + 169869312u);             //     131,072 B
  unsigned int* flags  = (unsigned int*)(ws + 170000384u);      //  8 * 256 B

  hipMemsetAsync(flags, 0, 8 * 256, stream);  // ws poisoned 0xAA pre-launch
  cvt_bf16<<<dim3(16384), dim3(256), 0, stream>>>(x, x_bf, 16777216);
  cvt_bf16<<<dim3(1024), dim3(256), 0, stream>>>(W_ih, w_bf, 1048576);
  gemm_xg<<<dim3(4096), dim3(256), 0, stream>>>(x_bf, w_bf, b_ih, b_hh, xg);

  void* args[] = {(void*)&xg, (void*)&W_hh, (void*)&h0, (void*)&c0,
                  (void*)&out, (void*)&hn, (void*)&cn, (void*)&h_buf, (void*)&flags};
  hipLaunchCooperativeKernel((const void*)lstm_rec, dim3(256), dim3(512), args, 0, stream);
}